// Round 5
// baseline (5083.123 us; speedup 1.0000x reference)
//
#include <hip/hip_runtime.h>

typedef _Float16 half2_t __attribute__((ext_vector_type(2)));
typedef _Float16 half8_t __attribute__((ext_vector_type(8)));
typedef float floatx4 __attribute__((ext_vector_type(4)));
typedef unsigned int u32;

#define BB 64
#define TT 2048
#define II 128
#define HH 256
#define CC 64
#define G3 (3*HH)          // 768
#define MTOT (BB*TT)       // 131072

static __device__ __forceinline__ float dot2f(half2_t a, half2_t b, float c) {
#if __has_builtin(__builtin_amdgcn_fdot2)
    return __builtin_amdgcn_fdot2(a, b, c, false);
#else
    return c + (float)a[0]*(float)b[0] + (float)a[1]*(float)b[1];
#endif
}

static __device__ __forceinline__ half2_t bch2(u32 x) {
    return __builtin_bit_cast(half2_t, x);
}

static __device__ __forceinline__ float fast_rcp(float x) {
    return __builtin_amdgcn_rcpf(x);
}

// quad butterfly sum via DPP quad_perm (pure VALU): after both stages all 4
// lanes of each quad hold the full sum. 0xB1=[1,0,3,2] (xor1), 0x4E=[2,3,0,1] (xor2).
static __device__ __forceinline__ float quad_allsum(float x) {
    int i = __builtin_bit_cast(int, x);
    int a = __builtin_amdgcn_mov_dpp(i, 0xB1, 0xF, 0xF, true);
    float y = x + __builtin_bit_cast(float, a);
    int k = __builtin_bit_cast(int, y);
    int b = __builtin_amdgcn_mov_dpp(k, 0x4E, 0xF, 0xF, true);
    return y + __builtin_bit_cast(float, b);
}

// ---------------------------------------------------------------------------
// MFMA GEMM: C[M,N] = A[M,K] @ W[N,K]^T + bias.  (validated in round 1)
// ---------------------------------------------------------------------------
template<typename AT, typename CT>
__global__ __launch_bounds__(256, 2)
void gemm_mfma(const AT* __restrict__ A, const float* __restrict__ W,
               const float* __restrict__ bias, CT* __restrict__ Cout,
               int M, int N, int K)
{
    __shared__ alignas(16) u32 As32[128 * 32];   // [row][8 slots of 16B], swizzled
    __shared__ alignas(16) u32 Bs32[64 * 32];

    const int tid  = threadIdx.x;
    const int lane = tid & 63;
    const int wave = tid >> 6;        // 0..3
    const int wm   = wave >> 1;       // 0..1 -> m offset 64*wm
    const int wn   = wave & 1;        // 0..1 -> n offset 32*wn
    const int m0   = blockIdx.y * 128;
    const int n0   = blockIdx.x * 64;
    const int lr   = lane & 15;       // fragment row/col
    const int lg   = lane >> 4;       // k-group 0..3

    floatx4 acc[4][2] = {};

    for (int kc = 0; kc < K; kc += 64) {
        // ---- stage A: 128 rows x 64 f16 = 1024 x 16B slots, 4 iters ----
        #pragma unroll
        for (int it = 0; it < 4; ++it) {
            const int s    = it * 256 + tid;
            const int row  = s >> 3;          // 0..127
            const int slot = s & 7;           // 0..7 (8 f16 each)
            const AT* src  = A + (size_t)(m0 + row) * K + kc + slot * 8;
            half8_t v;
            if constexpr (sizeof(AT) == 2) {
                v = *reinterpret_cast<const half8_t*>(src);
            } else {
                const float4* s4 = reinterpret_cast<const float4*>(src);
                float4 lo = s4[0], hi = s4[1];
                v[0] = (_Float16)lo.x; v[1] = (_Float16)lo.y;
                v[2] = (_Float16)lo.z; v[3] = (_Float16)lo.w;
                v[4] = (_Float16)hi.x; v[5] = (_Float16)hi.y;
                v[6] = (_Float16)hi.z; v[7] = (_Float16)hi.w;
            }
            const int sw = slot ^ (row & 7);
            *reinterpret_cast<half8_t*>(&As32[row * 32 + sw * 4]) = v;
        }
        // ---- stage B: 64 rows x 64 f16 = 512 slots, 2 iters (fp32 W) ----
        #pragma unroll
        for (int it = 0; it < 2; ++it) {
            const int s    = it * 256 + tid;
            const int row  = s >> 3;          // 0..63
            const int slot = s & 7;
            const float* src = W + (size_t)(n0 + row) * K + kc + slot * 8;
            const float4* s4 = reinterpret_cast<const float4*>(src);
            float4 lo = s4[0], hi = s4[1];
            half8_t v;
            v[0] = (_Float16)lo.x; v[1] = (_Float16)lo.y;
            v[2] = (_Float16)lo.z; v[3] = (_Float16)lo.w;
            v[4] = (_Float16)hi.x; v[5] = (_Float16)hi.y;
            v[6] = (_Float16)hi.z; v[7] = (_Float16)hi.w;
            const int sw = slot ^ (row & 7);
            *reinterpret_cast<half8_t*>(&Bs32[row * 32 + sw * 4]) = v;
        }
        __syncthreads();

        #pragma unroll
        for (int ks = 0; ks < 2; ++ks) {
            half8_t af[4], bf[2];
            #pragma unroll
            for (int fm = 0; fm < 4; ++fm) {
                const int row  = wm * 64 + fm * 16 + lr;
                const int slot = ks * 4 + lg;
                const int sw   = slot ^ (row & 7);
                af[fm] = *reinterpret_cast<const half8_t*>(&As32[row * 32 + sw * 4]);
            }
            #pragma unroll
            for (int fn = 0; fn < 2; ++fn) {
                const int row  = wn * 32 + fn * 16 + lr;
                const int slot = ks * 4 + lg;
                const int sw   = slot ^ (row & 7);
                bf[fn] = *reinterpret_cast<const half8_t*>(&Bs32[row * 32 + sw * 4]);
            }
            #pragma unroll
            for (int fm = 0; fm < 4; ++fm)
                #pragma unroll
                for (int fn = 0; fn < 2; ++fn)
                    acc[fm][fn] = __builtin_amdgcn_mfma_f32_16x16x32_f16(
                        af[fm], bf[fn], acc[fm][fn], 0, 0, 0);
        }
        __syncthreads();
    }

    // ---- epilogue: D[row=(lane>>4)*4+reg][col=lane&15] + bias ----
    #pragma unroll
    for (int fn = 0; fn < 2; ++fn) {
        const int n = n0 + wn * 32 + fn * 16 + lr;
        const float bv = bias[n];
        #pragma unroll
        for (int fm = 0; fm < 4; ++fm) {
            #pragma unroll
            for (int r = 0; r < 4; ++r) {
                const int m = m0 + wm * 64 + fm * 16 + lg * 4 + r;
                Cout[(size_t)m * N + n] = (CT)(acc[fm][fn][r] + bv);
            }
        }
    }
}

// ---------------------------------------------------------------------------
// Persistent GRU scan, v5: VALU dot2, weights UNDER the 128-reg ceiling.
// Evidence (v1/v2/v4): the allocator caps this kernel at 128 arch VGPRs no
// matter the waves_per_eu attribute; 192-reg weight arrays get AGPR-banked /
// spilled -> ~1 move per dot2 -> 2x hot loop. Fix: spread weights thinner.
// 1024 threads = 16 waves = exactly 4 waves/SIMD (amdgpu_waves_per_eu(4,4)
// -> 128-reg budget, and pins the allocator so it can't target 8 waves like
// v2 did when it chose 64 regs). Thread t: row j = t>>2, k-quarter kq = t&3.
// Weights: 3 gates x 32 half2 = 96 VGPRs; total demand ~125 <= 128.
// VALU dot issue per SIMD per step: 4 waves x 96 x 2cy = 768 cy (invariant).
//
// h in LDS, double-buffered, PADDED: each 64-value k-quarter stored at 144B
// stride (9x16B) so the 4 distinct ds_read_b128 addresses per instruction
// start at banks {4c, 4c+4q...} -> disjoint bank quads -> conflict-free
// (v2/v4's 128B stride aliased all slices onto the same banks: 6.7e7
// conflict cycles/dispatch, ~4cy extra per read).
// One barrier/step; DPP quad_allsum for the k-reduction; fast exp/rcp gates
// (numerics validated since v2); gx prefetched a FULL step ahead (final-step
// overrun lands in hbuf = valid workspace).
// ---------------------------------------------------------------------------
__global__ __attribute__((amdgpu_flat_work_group_size(1024, 1024),
                          amdgpu_waves_per_eu(4, 4)))
void gru_scan(const _Float16* __restrict__ gx,   // [B, T, 768] incl. b_ih
              const float* __restrict__ Whh,     // [768, 256]
              const float* __restrict__ bhh,     // [768]
              _Float16* __restrict__ hout)       // [B, T, 256]
{
    const int b  = blockIdx.x;
    const int t  = threadIdx.x;
    const int j  = t >> 2;          // row 0..255
    const int kq = t & 3;           // k-quarter (64 h values)

    // ---- weights: rows {j, 256+j, 512+j}, this thread's 64-k quarter ----
    half2_t w0[32], w1[32], w2[32];
    {
        const float2* q0 = reinterpret_cast<const float2*>(Whh + (size_t)j * HH + kq * 64);
        const float2* q1 = q0 + 128 * HH;    // +256 rows in float2 units
        const float2* q2 = q0 + 256 * HH;    // +512 rows
        #pragma unroll
        for (int i = 0; i < 32; ++i) {
            const float2 a = q0[i], c = q1[i], d = q2[i];
            w0[i] = half2_t{(_Float16)a.x, (_Float16)a.y};
            w1[i] = half2_t{(_Float16)c.x, (_Float16)c.y};
            w2[i] = half2_t{(_Float16)d.x, (_Float16)d.y};
        }
    }
    const float bh_r = bhh[j], bh_z = bhh[HH + j], bh_n = bhh[2*HH + j];

    // h double-buffered; quarter q of buffer f at f16 index f*288 + q*72
    // (144B stride). Pad f16s [64..72) per quarter are never read.
    __shared__ alignas(16) _Float16 Hs[2][288];
    if (t < 2 * 288) reinterpret_cast<_Float16*>(Hs)[t] = (_Float16)0.f;
    float hprev = 0.f;

    const _Float16* gp = gx + (size_t)b * TT * G3 + j;
    _Float16* op = hout + (size_t)b * TT * HH + j;
    const int hwr = (j >> 6) * 72 + (j & 63);   // this row's LDS write slot

    // step-0 input gates
    _Float16 pxr = gp[0], pxz = gp[HH], pxn = gp[2*HH];
    __syncthreads();

    for (int step = 0; step < TT; ++step) {
        // prefetch NEXT step's gx now (full-step slack covers HBM latency)
        const _Float16 nxr = gp[G3];
        const _Float16 nxz = gp[G3 + HH];
        const _Float16 nxn = gp[G3 + 2*HH];

        // ---- 8 x ds_read_b128 over this thread's padded k-quarter ----
        const uint4* hb = reinterpret_cast<const uint4*>(
            reinterpret_cast<const char*>(Hs[step & 1]) + kq * 144);
        float ar = 0.f, az = 0.f, an = 0.f;
        #pragma unroll
        for (int c = 0; c < 8; ++c) {
            const uint4 hv = hb[c];
            const half2_t ha = bch2(hv.x), hc = bch2(hv.y);
            const half2_t hd = bch2(hv.z), he = bch2(hv.w);
            ar = dot2f(ha, w0[4*c+0], ar); az = dot2f(ha, w1[4*c+0], az); an = dot2f(ha, w2[4*c+0], an);
            ar = dot2f(hc, w0[4*c+1], ar); az = dot2f(hc, w1[4*c+1], az); an = dot2f(hc, w2[4*c+1], an);
            ar = dot2f(hd, w0[4*c+2], ar); az = dot2f(hd, w1[4*c+2], az); an = dot2f(hd, w2[4*c+2], an);
            ar = dot2f(he, w0[4*c+3], ar); az = dot2f(he, w1[4*c+3], az); an = dot2f(he, w2[4*c+3], an);
        }
        // combine the 4 k-quarters: all quad lanes end with the full sums
        ar = quad_allsum(ar);
        az = quad_allsum(az);
        an = quad_allsum(an);

        const float r = fast_rcp(1.f + __expf(-((float)pxr + ar + bh_r)));
        const float z = fast_rcp(1.f + __expf(-((float)pxz + az + bh_z)));
        const float e = __expf(2.f * ((float)pxn + r * (an + bh_n)));
        const float n = 1.f - 2.f * fast_rcp(e + 1.f);
        const float hnew = (1.f - z) * n + z * hprev;
        hprev = hnew;

        if (kq == 0) {
            const _Float16 hf = (_Float16)hnew;
            Hs[(step + 1) & 1][hwr] = hf;    // next step's buffer
            op[0] = hf;                       // layer output (f16)
        }
        __syncthreads();   // next-buffer writes visible; current-buffer reads done

        gp += G3; op += HH;
        pxr = nxr; pxz = nxz; pxn = nxn;
    }
}

// ---------------------------------------------------------------------------
extern "C" void kernel_launch(void* const* d_in, const int* in_sizes, int n_in,
                              void* d_out, int out_size, void* d_ws, size_t ws_size,
                              hipStream_t stream) {
    const float* x    = (const float*)d_in[0];
    const float* Wih0 = (const float*)d_in[1];
    const float* Whh0 = (const float*)d_in[2];
    const float* bih0 = (const float*)d_in[3];
    const float* bhh0 = (const float*)d_in[4];
    const float* Wih1 = (const float*)d_in[5];
    const float* Whh1 = (const float*)d_in[6];
    const float* bih1 = (const float*)d_in[7];
    const float* bhh1 = (const float*)d_in[8];
    const float* fcw  = (const float*)d_in[9];
    const float* fcb  = (const float*)d_in[10];
    float* out = (float*)d_out;

    // workspace: gx buffer (201 MB, reused for both layers) + h buffer (64 MB)
    _Float16* gxbuf = (_Float16*)d_ws;
    _Float16* hbuf  = (_Float16*)((char*)d_ws + (size_t)MTOT * G3 * sizeof(_Float16));

    const dim3 blk(256);
    // 1) gx0 = x @ W_ih0^T + b_ih0
    gemm_mfma<float, _Float16><<<dim3(G3/64, MTOT/128), blk, 0, stream>>>(
        x, Wih0, bih0, gxbuf, MTOT, G3, II);
    // 2) scan layer 0 -> h0
    gru_scan<<<dim3(BB), dim3(1024), 0, stream>>>(gxbuf, Whh0, bhh0, hbuf);
    // 3) gx1 = h0 @ W_ih1^T + b_ih1 (overwrites gx buffer)
    gemm_mfma<_Float16, _Float16><<<dim3(G3/64, MTOT/128), blk, 0, stream>>>(
        hbuf, Wih1, bih1, gxbuf, MTOT, G3, HH);
    // 4) scan layer 1 -> h1 (overwrites h buffer)
    gru_scan<<<dim3(BB), dim3(1024), 0, stream>>>(gxbuf, Whh1, bhh1, hbuf);
    // 5) out = h1 @ fc_w^T + fc_b
    gemm_mfma<_Float16, float><<<dim3(CC/64, MTOT/128), blk, 0, stream>>>(
        hbuf, fcw, fcb, out, MTOT, CC, HH);
}

// Round 6
// 4840.276 us; speedup vs baseline: 1.0502x; 1.0502x over previous
//
#include <hip/hip_runtime.h>

typedef _Float16 half2_t __attribute__((ext_vector_type(2)));
typedef _Float16 half8_t __attribute__((ext_vector_type(8)));
typedef float floatx4 __attribute__((ext_vector_type(4)));
typedef unsigned int u32;

#define BB 64
#define TT 2048
#define II 128
#define HH 256
#define CC 64
#define G3 (3*HH)          // 768
#define MTOT (BB*TT)       // 131072

static __device__ __forceinline__ float dot2f(half2_t a, half2_t b, float c) {
#if __has_builtin(__builtin_amdgcn_fdot2)
    return __builtin_amdgcn_fdot2(a, b, c, false);
#else
    return c + (float)a[0]*(float)b[0] + (float)a[1]*(float)b[1];
#endif
}

static __device__ __forceinline__ half2_t bch2(u32 x) {
    return __builtin_bit_cast(half2_t, x);
}

static __device__ __forceinline__ float fast_rcp(float x) {
    return __builtin_amdgcn_rcpf(x);
}

// DPP quad_perm helpers (pure VALU cross-lane, no LDS pipe).
// 0xB1 = [1,0,3,2] (xor 1), 0x4E = [2,3,0,1] (xor 2).
static __device__ __forceinline__ float pair_sum(float x) {   // lanes t,t^1 both get sum
    int i = __builtin_bit_cast(int, x);
    int a = __builtin_amdgcn_mov_dpp(i, 0xB1, 0xF, 0xF, true);
    return x + __builtin_bit_cast(float, a);
}
static __device__ __forceinline__ float dpp_xor2(float x) {   // value from lane t^2
    int i = __builtin_bit_cast(int, x);
    int a = __builtin_amdgcn_mov_dpp(i, 0x4E, 0xF, 0xF, true);
    return __builtin_bit_cast(float, a);
}

// ---------------------------------------------------------------------------
// MFMA GEMM: C[M,N] = A[M,K] @ W[N,K]^T + bias.  (validated in round 1)
// ---------------------------------------------------------------------------
template<typename AT, typename CT>
__global__ __launch_bounds__(256, 2)
void gemm_mfma(const AT* __restrict__ A, const float* __restrict__ W,
               const float* __restrict__ bias, CT* __restrict__ Cout,
               int M, int N, int K)
{
    __shared__ alignas(16) u32 As32[128 * 32];   // [row][8 slots of 16B], swizzled
    __shared__ alignas(16) u32 Bs32[64 * 32];

    const int tid  = threadIdx.x;
    const int lane = tid & 63;
    const int wave = tid >> 6;        // 0..3
    const int wm   = wave >> 1;       // 0..1 -> m offset 64*wm
    const int wn   = wave & 1;        // 0..1 -> n offset 32*wn
    const int m0   = blockIdx.y * 128;
    const int n0   = blockIdx.x * 64;
    const int lr   = lane & 15;       // fragment row/col
    const int lg   = lane >> 4;       // k-group 0..3

    floatx4 acc[4][2] = {};

    for (int kc = 0; kc < K; kc += 64) {
        // ---- stage A: 128 rows x 64 f16 = 1024 x 16B slots, 4 iters ----
        #pragma unroll
        for (int it = 0; it < 4; ++it) {
            const int s    = it * 256 + tid;
            const int row  = s >> 3;          // 0..127
            const int slot = s & 7;           // 0..7 (8 f16 each)
            const AT* src  = A + (size_t)(m0 + row) * K + kc + slot * 8;
            half8_t v;
            if constexpr (sizeof(AT) == 2) {
                v = *reinterpret_cast<const half8_t*>(src);
            } else {
                const float4* s4 = reinterpret_cast<const float4*>(src);
                float4 lo = s4[0], hi = s4[1];
                v[0] = (_Float16)lo.x; v[1] = (_Float16)lo.y;
                v[2] = (_Float16)lo.z; v[3] = (_Float16)lo.w;
                v[4] = (_Float16)hi.x; v[5] = (_Float16)hi.y;
                v[6] = (_Float16)hi.z; v[7] = (_Float16)hi.w;
            }
            const int sw = slot ^ (row & 7);
            *reinterpret_cast<half8_t*>(&As32[row * 32 + sw * 4]) = v;
        }
        // ---- stage B: 64 rows x 64 f16 = 512 slots, 2 iters (fp32 W) ----
        #pragma unroll
        for (int it = 0; it < 2; ++it) {
            const int s    = it * 256 + tid;
            const int row  = s >> 3;          // 0..63
            const int slot = s & 7;
            const float* src = W + (size_t)(n0 + row) * K + kc + slot * 8;
            const float4* s4 = reinterpret_cast<const float4*>(src);
            float4 lo = s4[0], hi = s4[1];
            half8_t v;
            v[0] = (_Float16)lo.x; v[1] = (_Float16)lo.y;
            v[2] = (_Float16)lo.z; v[3] = (_Float16)lo.w;
            v[4] = (_Float16)hi.x; v[5] = (_Float16)hi.y;
            v[6] = (_Float16)hi.z; v[7] = (_Float16)hi.w;
            const int sw = slot ^ (row & 7);
            *reinterpret_cast<half8_t*>(&Bs32[row * 32 + sw * 4]) = v;
        }
        __syncthreads();

        #pragma unroll
        for (int ks = 0; ks < 2; ++ks) {
            half8_t af[4], bf[2];
            #pragma unroll
            for (int fm = 0; fm < 4; ++fm) {
                const int row  = wm * 64 + fm * 16 + lr;
                const int slot = ks * 4 + lg;
                const int sw   = slot ^ (row & 7);
                af[fm] = *reinterpret_cast<const half8_t*>(&As32[row * 32 + sw * 4]);
            }
            #pragma unroll
            for (int fn = 0; fn < 2; ++fn) {
                const int row  = wn * 32 + fn * 16 + lr;
                const int slot = ks * 4 + lg;
                const int sw   = slot ^ (row & 7);
                bf[fn] = *reinterpret_cast<const half8_t*>(&Bs32[row * 32 + sw * 4]);
            }
            #pragma unroll
            for (int fm = 0; fm < 4; ++fm)
                #pragma unroll
                for (int fn = 0; fn < 2; ++fn)
                    acc[fm][fn] = __builtin_amdgcn_mfma_f32_16x16x32_f16(
                        af[fm], bf[fn], acc[fm][fn], 0, 0, 0);
        }
        __syncthreads();
    }

    // ---- epilogue: D[row=(lane>>4)*4+reg][col=lane&15] + bias ----
    #pragma unroll
    for (int fn = 0; fn < 2; ++fn) {
        const int n = n0 + wn * 32 + fn * 16 + lr;
        const float bv = bias[n];
        #pragma unroll
        for (int fm = 0; fm < 4; ++fm) {
            #pragma unroll
            for (int r = 0; r < 4; ++r) {
                const int m = m0 + wm * 64 + fm * 16 + lg * 4 + r;
                Cout[(size_t)m * N + n] = (CT)(acc[fm][fn][r] + bv);
            }
        }
    }
}

// ---------------------------------------------------------------------------
// Persistent GRU scan, v6: VALU dot2, z-gate weights in LDS.
// Evidence (v1/v2/v4/v5): allocator gives arch-VGPR = unified-budget/2
// (512thr->128, 1024thr->64); any weight overflow is AGPR-banked at ~1 VALU
// move per use per step. Fix: shrink reg-resident weights to 128 half2
// (r + n gates) and move the z-gate's 64 half2/thread to LDS, read per step
// via 16 ds_read_b128 -- LDS-pipe cycles, ZERO VALU instructions.
//
// LDS: 512 thread-private 272B blocks (64 u32 data + 4 pad) = 136 KB.
// Stride 272B => start bank 4t mod 32, uniform: each b128 wave-read moves
// 1024B in the structural-minimum 8 passes, no excess conflicts. Each
// thread reads back exactly what it wrote (private block) => layout trivially
// consistent. h double-buffered as padded halves (68-u32 stride so the two
// kh half-reads hit disjoint bank groups; v4's 2-way alias gone).
// One barrier/step; DPP pair_sum reduction; fast exp/rcp gates; gx
// prefetched a FULL step ahead (final overrun lands in hbuf workspace).
// Expected step: 768cy dots + ~300 residual-AGPR tax + ~200 gates ~= 1250cy.
// ---------------------------------------------------------------------------
__global__ __attribute__((amdgpu_flat_work_group_size(512, 512),
                          amdgpu_waves_per_eu(2, 2)))
void gru_scan(const _Float16* __restrict__ gx,   // [B, T, 768] incl. b_ih
              const float* __restrict__ Whh,     // [768, 256]
              const float* __restrict__ bhh,     // [768]
              _Float16* __restrict__ hout)       // [B, T, 256]
{
    const int b  = blockIdx.x;
    const int t  = threadIdx.x;
    const int j  = t >> 1;          // 0..255
    const int kh = t & 1;           // k-half

    __shared__ alignas(16) u32 WzL[512 * 68];    // z-gate weights, 272B/thread
    __shared__ alignas(16) u32 HsU[2][136];      // h double-buffered, padded halves

    // ---- r,n gate weights in registers (64 half2 each = 128 regs) ----
    half2_t w0[64], w2[64];
    {
        const float2* q0 = reinterpret_cast<const float2*>(Whh + (size_t)j * HH + kh * 128);
        const float2* q2 = q0 + 256 * HH;    // +512 rows in float2 units
        #pragma unroll
        for (int i = 0; i < 64; ++i) {
            const float2 a = q0[i], d = q2[i];
            w0[i] = half2_t{(_Float16)a.x, (_Float16)a.y};
            w2[i] = half2_t{(_Float16)d.x, (_Float16)d.y};
        }
    }
    // ---- z-gate weights into this thread's private LDS block ----
    {
        const float2* q1 = reinterpret_cast<const float2*>(Whh + (size_t)(256 + j) * HH + kh * 128);
        u32* wz = WzL + t * 68;
        #pragma unroll
        for (int i = 0; i < 64; ++i) {
            const float2 c = q1[i];
            const half2_t hp{(_Float16)c.x, (_Float16)c.y};
            wz[i] = __builtin_bit_cast(u32, hp);
        }
    }
    const float bh_r = bhh[j], bh_z = bhh[HH + j], bh_n = bhh[2*HH + j];

    if (t < 272) reinterpret_cast<u32*>(HsU)[t] = 0u;   // zero both h buffers
    float hprev = 0.f;

    const _Float16* gp = gx + (size_t)b * TT * G3 + j;
    u32* opw = (u32*)(hout + (size_t)b * TT * HH);

    // step-0 input gates
    _Float16 pxr = gp[0], pxz = gp[HH], pxn = gp[2*HH];
    __syncthreads();

    for (int step = 0; step < TT; ++step) {
        // prefetch NEXT step's gx now (full-step slack covers HBM latency)
        const _Float16 nxr = gp[G3];
        const _Float16 nxz = gp[G3 + HH];
        const _Float16 nxn = gp[G3 + 2*HH];

        // 16 x ds_read_b128 (h) + 16 x ds_read_b128 (z-weights)
        const uint4* hb  = reinterpret_cast<const uint4*>(HsU[step & 1] + kh * 68);
        const uint4* wzv = reinterpret_cast<const uint4*>(WzL + t * 68);
        float ar = 0.f, az = 0.f, an = 0.f;
        #pragma unroll
        for (int c = 0; c < 16; ++c) {
            const uint4 hv = hb[c];
            const uint4 wv = wzv[c];
            const half2_t ha = bch2(hv.x), hc = bch2(hv.y);
            const half2_t hd = bch2(hv.z), he = bch2(hv.w);
            ar = dot2f(ha, w0[4*c+0], ar); az = dot2f(ha, bch2(wv.x), az); an = dot2f(ha, w2[4*c+0], an);
            ar = dot2f(hc, w0[4*c+1], ar); az = dot2f(hc, bch2(wv.y), az); an = dot2f(hc, w2[4*c+1], an);
            ar = dot2f(hd, w0[4*c+2], ar); az = dot2f(hd, bch2(wv.z), az); an = dot2f(hd, w2[4*c+2], an);
            ar = dot2f(he, w0[4*c+3], ar); az = dot2f(he, bch2(wv.w), az); an = dot2f(he, w2[4*c+3], an);
        }
        // combine k-halves: lanes t,t^1 (same j) both end with the full sum
        ar = pair_sum(ar);
        az = pair_sum(az);
        an = pair_sum(an);

        const float r = fast_rcp(1.f + __expf(-((float)pxr + ar + bh_r)));
        const float z = fast_rcp(1.f + __expf(-((float)pxz + az + bh_z)));
        const float e = __expf(2.f * ((float)pxn + r * (an + bh_n)));
        const float n = 1.f - 2.f * fast_rcp(e + 1.f);
        const float hnew = (1.f - z) * n + z * hprev;
        hprev = hnew;

        // pack pair {h[j], h[j+1]} on lanes t%4==0 (j even, kh 0)
        const float hoth = dpp_xor2(hnew);     // row j^1's value
        if ((t & 3) == 0) {
            const half2_t hp{(_Float16)hnew, (_Float16)hoth};
            const u32 pu = __builtin_bit_cast(u32, hp);
            const int m = t >> 2;              // h-pair index 0..127
            HsU[(step + 1) & 1][(m >> 6) * 68 + (m & 63)] = pu;  // next buffer (padded)
            opw[m] = pu;                                          // layer output
        }
        __syncthreads();   // next-buffer writes visible; current-buffer reads done

        gp += G3; opw += HH/2;
        pxr = nxr; pxz = nxz; pxn = nxn;
    }
}

// ---------------------------------------------------------------------------
extern "C" void kernel_launch(void* const* d_in, const int* in_sizes, int n_in,
                              void* d_out, int out_size, void* d_ws, size_t ws_size,
                              hipStream_t stream) {
    const float* x    = (const float*)d_in[0];
    const float* Wih0 = (const float*)d_in[1];
    const float* Whh0 = (const float*)d_in[2];
    const float* bih0 = (const float*)d_in[3];
    const float* bhh0 = (const float*)d_in[4];
    const float* Wih1 = (const float*)d_in[5];
    const float* Whh1 = (const float*)d_in[6];
    const float* bih1 = (const float*)d_in[7];
    const float* bhh1 = (const float*)d_in[8];
    const float* fcw  = (const float*)d_in[9];
    const float* fcb  = (const float*)d_in[10];
    float* out = (float*)d_out;

    // workspace: gx buffer (201 MB, reused for both layers) + h buffer (64 MB)
    _Float16* gxbuf = (_Float16*)d_ws;
    _Float16* hbuf  = (_Float16*)((char*)d_ws + (size_t)MTOT * G3 * sizeof(_Float16));

    const dim3 blk(256);
    // 1) gx0 = x @ W_ih0^T + b_ih0
    gemm_mfma<float, _Float16><<<dim3(G3/64, MTOT/128), blk, 0, stream>>>(
        x, Wih0, bih0, gxbuf, MTOT, G3, II);
    // 2) scan layer 0 -> h0
    gru_scan<<<dim3(BB), dim3(512), 0, stream>>>(gxbuf, Whh0, bhh0, hbuf);
    // 3) gx1 = h0 @ W_ih1^T + b_ih1 (overwrites gx buffer)
    gemm_mfma<_Float16, _Float16><<<dim3(G3/64, MTOT/128), blk, 0, stream>>>(
        hbuf, Wih1, bih1, gxbuf, MTOT, G3, HH);
    // 4) scan layer 1 -> h1 (overwrites h buffer)
    gru_scan<<<dim3(BB), dim3(512), 0, stream>>>(gxbuf, Whh1, bhh1, hbuf);
    // 5) out = h1 @ fc_w^T + fc_b
    gemm_mfma<_Float16, float><<<dim3(CC/64, MTOT/128), blk, 0, stream>>>(
        hbuf, fcw, fcb, out, MTOT, CC, HH);
}